// Round 8
// baseline (7798.161 us; speedup 1.0000x reference)
//
#include <hip/hip_runtime.h>
#include <hip/hip_bf16.h>

// Problem constants
#define B_    32
#define TO_   256
#define T_    257        // To+1 decode steps
#define H_    512
#define V_    10000
#define TI_   1024
#define NROW_ 8224       // T_*B_
#define NB_   256        // blocks in cooperative kernel
#define SPINCAP 150000

using f32x4 = __attribute__((ext_vector_type(4))) float;
using s16x8 = __attribute__((ext_vector_type(8))) short;
typedef unsigned long long ull;

struct Ptrs {
  const int* padded;
  const float* enc;
  const float* emb;
  const float *Wih0, *Whh0, *bih0, *bhh0;
  const float *Wih1, *Whh1, *bih1, *bhh1;
  const float *W1, *b1, *W2, *b2;
  float* out;
  // workspace
  unsigned short *mlpin;   // [257][32][1024] bf16  (=[h1 | att_c])
  unsigned short *embt;    // [257][32][512] bf16; tanhv overlays after kA
  unsigned short *tanhv;   // [8224][512] bf16 (== embt region)
  unsigned short *W0c;     // [2048][1536] bf16 rows g'=j*4+q = [Wih0 | Whh0]; W2b overlays
  unsigned short *W1c;     // [2048][1024] bf16 rows g'=j*4+q = [Wih1 | Whh1]
  unsigned short *W1b;     // [512][1024] bf16
  unsigned short *W2b;     // [10000][512] bf16 (== W0c region, kprep2)
  float *bias0c, *bias1c;  // [2048] combined biases, gate-interleaved
  float *u;                // [2][32][512] f32 unnormalized context (sc1 atomicAdd)
  float *Zb;               // [2][32] softmax denominators (sc1 atomicAdd)
  unsigned short *Xh0;     // [2][32][512] bf16 h0 state
  unsigned short *Xh1;     // [2][32][512] bf16 h1 state
  float *Xh1f;             // [2][32][512] f32 h1 state (attention staging)
  unsigned *arrX;          // [128*4] S1-done flags (GEMM blocks)
  unsigned *arrY;          // [256*4] pre-S34-ready flags (all blocks)
  unsigned *marr;          // [256*4] S34-done flags
  unsigned *ibar;          // [256*4] init barrier flags
  float *rowsum;           // [8224]
  float *lablog;           // [8224]
};

__device__ __forceinline__ unsigned short f2b(float f){
  __hip_bfloat16 h = __float2bfloat16(f);
  unsigned short r; __builtin_memcpy(&r, &h, 2); return r;
}
__device__ __forceinline__ float b2f(unsigned short u){
  unsigned v = ((unsigned)u) << 16; float f; __builtin_memcpy(&f, &v, 4); return f;
}
__device__ __forceinline__ float sigf(float x){ return 1.f / (1.f + expf(-x)); }

// ---- agent-scope (sc1, L3) relaxed atomics ----
__device__ __forceinline__ float aldf(const float* p){
  return __hip_atomic_load(p, __ATOMIC_RELAXED, __HIP_MEMORY_SCOPE_AGENT);
}
__device__ __forceinline__ unsigned aldw(const unsigned* p){
  return __hip_atomic_load(p, __ATOMIC_RELAXED, __HIP_MEMORY_SCOPE_AGENT);
}
__device__ __forceinline__ ull aldu(const ull* p){
  return __hip_atomic_load(p, __ATOMIC_RELAXED, __HIP_MEMORY_SCOPE_AGENT);
}
__device__ __forceinline__ void astf(float* p, float v){
  __hip_atomic_store(p, v, __ATOMIC_RELAXED, __HIP_MEMORY_SCOPE_AGENT);
}
__device__ __forceinline__ void astu(ull* p, ull v){
  __hip_atomic_store(p, v, __ATOMIC_RELAXED, __HIP_MEMORY_SCOPE_AGENT);
}
__device__ __forceinline__ void astw(unsigned* p, unsigned v){
  __hip_atomic_store(p, v, __ATOMIC_RELAXED, __HIP_MEMORY_SCOPE_AGENT);
}
#define DRAIN asm volatile("s_waitcnt vmcnt(0)" ::: "memory")

// init-time full-grid flag barrier (bounded)
__device__ __forceinline__ void gbarInit(unsigned* bar){
  DRAIN; __syncthreads();
  if (threadIdx.x < 64){
    const int l = threadIdx.x;
    if (l == 0) astw(bar + blockIdx.x * 4, 1u);
    int spin = 0;
    for (;;){
      unsigned f0 = aldw(bar + (l      ) * 4);
      unsigned f1 = aldw(bar + (l +  64) * 4);
      unsigned f2 = aldw(bar + (l + 128) * 4);
      unsigned f3 = aldw(bar + (l + 192) * 4);
      if (__all((f0 >= 1u) & (f1 >= 1u) & (f2 >= 1u) & (f3 >= 1u))) break;
      if (++spin > SPINCAP) break;
      __builtin_amdgcn_s_sleep(1);
    }
  }
  __syncthreads();
}

// ------------------------------------------------------------------
__global__ __launch_bounds__(256) void kprep(Ptrs P){
  const int stride = gridDim.x * blockDim.x;
  const int i0 = blockIdx.x * blockDim.x + threadIdx.x;
  for (int i = i0; i < 128 * 4; i += stride) P.arrX[i] = 0u;
  for (int i = i0; i < 256 * 4; i += stride){ P.arrY[i] = 0u; P.marr[i] = 0u; P.ibar[i] = 0u; }
  for (int i = i0; i < T_ * B_ * 512; i += stride){
    int k = i & 511, tb = i >> 9, b = tb & 31, t = tb >> 5;
    int tok = (t == 0) ? 1 : P.padded[b * TO_ + (t - 1)];
    P.embt[i] = f2b(P.emb[(size_t)tok * 512 + k]);
  }
  for (int i = i0; i < 2048 * 1536; i += stride){
    int k = i % 1536, gp = i / 1536;
    int j = gp >> 2, q = gp & 3, g = q * 512 + j;
    float v = (k < 1024) ? P.Wih0[(size_t)g * 1024 + k] : P.Whh0[(size_t)g * 512 + (k - 1024)];
    P.W0c[i] = f2b(v);
  }
  for (int i = i0; i < 2048 * 1024; i += stride){
    int k = i & 1023, gp = i >> 10;
    int j = gp >> 2, q = gp & 3, g = q * 512 + j;
    float v = (k < 512) ? P.Wih1[(size_t)g * 512 + k] : P.Whh1[(size_t)g * 512 + (k - 512)];
    P.W1c[i] = f2b(v);
  }
  for (int i = i0; i < 2048; i += stride){
    int j = i >> 2, q = i & 3, g = q * 512 + j;
    P.bias0c[i] = P.bih0[g] + P.bhh0[g];
    P.bias1c[i] = P.bih1[g] + P.bhh1[g];
  }
  for (int i = i0; i < 512 * 1024; i += stride) P.W1b[i] = f2b(P.W1[i]);
  for (int i = i0; i < NROW_; i += stride) P.rowsum[i] = 0.f;
}

__global__ __launch_bounds__(256) void kprep2(Ptrs P){
  const int stride = gridDim.x * blockDim.x;
  const int i0 = blockIdx.x * blockDim.x + threadIdx.x;
  for (int i = i0; i < V_ * 512; i += stride) P.W2b[i] = f2b(P.W2[i]);
}

// ------------------------------------------------------------------
// Phase A. Per step t (tv = t+1):
//  GEMM (0-127):  S1a (e+h0 MFMAs) | wait marr>=t | S1b (u*rZ seg) -> h0,
//                 arrX ; wait arrX ; S2 -> h1/Xh1f ; arrY ; mlpin h1.
//  128-159:       wait own-batch marr>=t ; write mlpin att_c(t-1) ; arrY.
//  160-223:       clear u[p] ; arrY.    224: clear Zb[p] ; arrY.  rest: arrY.
//  all: wait arrY>=tv ; S34 scores+softmax -> atomicAdd u[p],Zb[p] ; marr.
__global__ __launch_bounds__(256, 1) void kA(Ptrs P){
  __shared__ __align__(16) unsigned short enc_s[128 * 512]; // 128 KB, XOR-swizzled
  __shared__ float h1_s[512];
  __shared__ float w_s[128];
  __shared__ float gate_s[2][32][17];
  __shared__ float h_s[32][4];
  __shared__ float zred[2];
  const int bb = blockIdx.x, tid = threadIdx.x;
  const int b_att = bb >> 3, tc = bb & 7;

  { // stage encoder slice -> LDS bf16, byte^((row&7)<<4) swizzle
    const float* ep = P.enc + ((size_t)b_att * TI_ + (size_t)tc * 128) * H_;
    for (int idx = tid; idx < 128 * 512; idx += 256){
      int row = idx >> 9;
      unsigned byteoff = ((unsigned)idx * 2u) ^ ((unsigned)(row & 7) << 4);
      enc_s[byteoff >> 1] = f2b(ep[idx]);
    }
  }
  { // init recurrent state
    int g = bb * 256 + tid;
    if (g < 32768){ astf(P.u + g, 0.f); astf(P.Xh1f + g, 0.f); }
    if (g < 16384){ astw((unsigned*)P.Xh0 + g, 0u); astw((unsigned*)P.Xh1 + g, 0u); }
    if (g < 64) astf(P.Zb + g, (g >= 32) ? 1.f : 0.f);   // Zb[1]=1 for t=0
  }
  gbarInit(P.ibar);

  const int wv = tid >> 6, l = tid & 63, lr = l & 15, lk = l >> 4;
  const int bh = wv & 1, kh = wv >> 1;          // batch-half, K-half
  const int batch = bh * 16 + lr;
  const int eidx = tid - 128, eb = eidx >> 2, ejl = eidx & 3;
  const bool isGemm = bb < 128;
  float c0r = 0.f, c1r = 0.f;

  for (int t = 0; t < T_; ++t){
    const int p = t & 1, pp = p ^ 1;
    const unsigned tv = (unsigned)t + 1u;
    if (isGemm){
      // ---- S1a: e-seg + h0-seg MFMAs (independent of attc(t-1)) ----
      const unsigned short* Brow = P.W0c + (size_t)(bb * 16 + lr) * 1536;
      const unsigned short* Erow = P.embt + ((size_t)t * 32 + batch) * 512;
      f32x4 acc = {0.f, 0.f, 0.f, 0.f};
      #pragma unroll
      for (int ks = 0; ks < 8; ++ks){
        const int kb = (kh * 8 + ks) * 32 + lk * 8;
        s16x8 a = *(const s16x8*)(Erow + kb);
        s16x8 b = *(const s16x8*)(Brow + kb);
        acc = __builtin_amdgcn_mfma_f32_16x16x32_bf16(a, b, acc, 0, 0, 0);
      }
      {
        const ull* Hrow = (const ull*)(P.Xh0 + pp * 16384 + batch * 512);
        #pragma unroll
        for (int ks = 0; ks < 8; ++ks){
          const int kb = (kh * 8 + ks) * 32 + lk * 8;
          ull d0 = aldu(Hrow + (kb >> 2)), d1 = aldu(Hrow + (kb >> 2) + 1);
          s16x8 a; __builtin_memcpy(&a, &d0, 8); __builtin_memcpy(((char*)&a) + 8, &d1, 8);
          s16x8 b = *(const s16x8*)(Brow + 1024 + kb);
          acc = __builtin_amdgcn_mfma_f32_16x16x32_bf16(a, b, acc, 0, 0, 0);
        }
      }
      // ---- wait: S34(t-1) contributions all in (marr over all 256 blocks) ----
      if (t > 0){
        if (tid < 64){
          const unsigned want = (unsigned)t;
          int spin = 0;
          for (;;){
            unsigned f0 = aldw(P.marr + (tid      ) * 4);
            unsigned f1 = aldw(P.marr + (tid +  64) * 4);
            unsigned f2 = aldw(P.marr + (tid + 128) * 4);
            unsigned f3 = aldw(P.marr + (tid + 192) * 4);
            if (__all((f0 >= want) & (f1 >= want) & (f2 >= want) & (f3 >= want))) break;
            if (++spin > SPINCAP) break;
            __builtin_amdgcn_s_sleep(1);
          }
        }
        __syncthreads();
      }
      // ---- S1b: att_c segment from u[pp]*rZ ----
      {
        const float* Urow = P.u + pp * 16384 + batch * 512;
        const float rZ = 1.f / aldf(P.Zb + pp * 32 + batch);
        #pragma unroll
        for (int ks = 0; ks < 8; ++ks){
          const int kb = (kh * 8 + ks) * 32 + lk * 8;
          ull dd[4];
          dd[0] = aldu((const ull*)(Urow + kb));
          dd[1] = aldu((const ull*)(Urow + kb + 2));
          dd[2] = aldu((const ull*)(Urow + kb + 4));
          dd[3] = aldu((const ull*)(Urow + kb + 6));
          float uf[8]; __builtin_memcpy(uf, dd, 32);
          s16x8 a;
          #pragma unroll
          for (int e = 0; e < 8; ++e) a[e] = (short)f2b(uf[e] * rZ);
          s16x8 b = *(const s16x8*)(Brow + 512 + kb);
          acc = __builtin_amdgcn_mfma_f32_16x16x32_bf16(a, b, acc, 0, 0, 0);
        }
      }
      #pragma unroll
      for (int j = 0; j < 4; ++j) gate_s[kh][bh * 16 + lk * 4 + j][lr] = acc[j];
      __syncthreads();
      if (tid >= 128){
        const float* bs = P.bias0c + bb * 16 + ejl * 4;
        float ii = sigf (gate_s[0][eb][ejl * 4 + 0] + gate_s[1][eb][ejl * 4 + 0] + bs[0]);
        float ff = sigf (gate_s[0][eb][ejl * 4 + 1] + gate_s[1][eb][ejl * 4 + 1] + bs[1]);
        float gg = tanhf(gate_s[0][eb][ejl * 4 + 2] + gate_s[1][eb][ejl * 4 + 2] + bs[2]);
        float oo = sigf (gate_s[0][eb][ejl * 4 + 3] + gate_s[1][eb][ejl * 4 + 3] + bs[3]);
        float cn = ff * c0r + ii * gg; c0r = cn;
        h_s[eb][ejl] = oo * tanhf(cn);
      }
      __syncthreads();
      if (tid < 32){
        unsigned short hb[4];
        #pragma unroll
        for (int jl = 0; jl < 4; ++jl) hb[jl] = f2b(h_s[tid][jl]);
        ull v; __builtin_memcpy(&v, hb, 8);
        astu((ull*)(P.Xh0 + p * 16384 + tid * 512 + bb * 4), v);
      }
      DRAIN; __syncthreads();
      if (tid == 0) astw(P.arrX + bb * 4, tv);
      // ---- arrX wait (128 blocks) ----
      if (tid < 64){
        int spin = 0;
        for (;;){
          unsigned f0 = aldw(P.arrX + tid * 4), f1 = aldw(P.arrX + (tid + 64) * 4);
          if (__all((f0 >= tv) & (f1 >= tv))) break;
          if (++spin > SPINCAP) break;
          __builtin_amdgcn_s_sleep(1);
        }
      }
      __syncthreads();
      // ---- S2: layer-1 gates ----
      {
        const unsigned short* Brow1 = P.W1c + (size_t)(bb * 16 + lr) * 1024;
        const ull* H0r = (const ull*)(P.Xh0 + p * 16384 + batch * 512);
        const ull* H1r = (const ull*)(P.Xh1 + pp * 16384 + batch * 512);
        f32x4 acc2 = {0.f, 0.f, 0.f, 0.f};
        #pragma unroll
        for (int ks = 0; ks < 8; ++ks){
          const int kb = (kh * 8 + ks) * 32 + lk * 8;
          ull d0 = aldu(H0r + (kb >> 2)), d1 = aldu(H0r + (kb >> 2) + 1);
          s16x8 a; __builtin_memcpy(&a, &d0, 8); __builtin_memcpy(((char*)&a) + 8, &d1, 8);
          s16x8 b = *(const s16x8*)(Brow1 + kb);
          acc2 = __builtin_amdgcn_mfma_f32_16x16x32_bf16(a, b, acc2, 0, 0, 0);
        }
        #pragma unroll
        for (int ks = 0; ks < 8; ++ks){
          const int kb = (kh * 8 + ks) * 32 + lk * 8;
          ull d0 = aldu(H1r + (kb >> 2)), d1 = aldu(H1r + (kb >> 2) + 1);
          s16x8 a; __builtin_memcpy(&a, &d0, 8); __builtin_memcpy(((char*)&a) + 8, &d1, 8);
          s16x8 b = *(const s16x8*)(Brow1 + 512 + kb);
          acc2 = __builtin_amdgcn_mfma_f32_16x16x32_bf16(a, b, acc2, 0, 0, 0);
        }
        #pragma unroll
        for (int j = 0; j < 4; ++j) gate_s[kh][bh * 16 + lk * 4 + j][lr] = acc2[j];
      }
      __syncthreads();
      if (tid >= 128){
        const float* bs = P.bias1c + bb * 16 + ejl * 4;
        float ii = sigf (gate_s[0][eb][ejl * 4 + 0] + gate_s[1][eb][ejl * 4 + 0] + bs[0]);
        float ff = sigf (gate_s[0][eb][ejl * 4 + 1] + gate_s[1][eb][ejl * 4 + 1] + bs[1]);
        float gg = tanhf(gate_s[0][eb][ejl * 4 + 2] + gate_s[1][eb][ejl * 4 + 2] + bs[2]);
        float oo = sigf (gate_s[0][eb][ejl * 4 + 3] + gate_s[1][eb][ejl * 4 + 3] + bs[3]);
        float cn = ff * c1r + ii * gg; c1r = cn;
        h_s[eb][ejl] = oo * tanhf(cn);
      }
      __syncthreads();
      if (tid < 32){
        unsigned short hb[4];
        #pragma unroll
        for (int jl = 0; jl < 4; ++jl) hb[jl] = f2b(h_s[tid][jl]);
        ull vb; __builtin_memcpy(&vb, hb, 8);
        astu((ull*)(P.Xh1 + p * 16384 + tid * 512 + bb * 4), vb);
        ull w0, w1;
        __builtin_memcpy(&w0, &h_s[tid][0], 8);
        __builtin_memcpy(&w1, &h_s[tid][2], 8);
        ull* dst = (ull*)P.Xh1f + ((p * 16384 + tid * 512 + bb * 4) >> 1);
        astu(dst, w0); astu(dst + 1, w1);
      }
      DRAIN; __syncthreads();
      if (tid == 0) astw(P.arrY + bb * 4, tv);
      if (tid < 32){                             // mlpin h1: after flag (off-path)
        unsigned short hb[4];
        #pragma unroll
        for (int jl = 0; jl < 4; ++jl) hb[jl] = f2b(h_s[tid][jl]);
        ull vb; __builtin_memcpy(&vb, hb, 8);
        *(ull*)(P.mlpin + ((size_t)t * 32 + tid) * 1024 + bb * 4) = vb;
      }
    } else if (bb < 160){
      if (t > 0){
        const int b = bb - 128;
        if (tid < 64){
          const unsigned want = (unsigned)t;
          int spin = 0;
          for (;;){
            unsigned f = (tid < 8) ? aldw(P.marr + (b * 8 + tid) * 4) : want;
            if (__all(f >= want)) break;
            if (++spin > SPINCAP) break;
            __builtin_amdgcn_s_sleep(1);
          }
        }
        __syncthreads();
        const float rZ = 1.f / aldf(P.Zb + pp * 32 + b);
        ull v = aldu((const ull*)(P.u + pp * 16384 + b * 512) + tid);
        float f2[2]; __builtin_memcpy(f2, &v, 8);
        unsigned pk = (unsigned)f2b(f2[0] * rZ) | ((unsigned)f2b(f2[1] * rZ) << 16);
        *(unsigned*)(P.mlpin + ((size_t)(t - 1) * 32 + b) * 1024 + 512 + tid * 2) = pk;
        DRAIN;
      }
      __syncthreads();
      if (tid == 0) astw(P.arrY + bb * 4, tv);
    } else if (bb < 224){
      astf(P.u + p * 16384 + (bb - 160) * 256 + tid, 0.f);   // clear u[p] for S34(t)
      DRAIN; __syncthreads();
      if (tid == 0) astw(P.arrY + bb * 4, tv);
    } else if (bb == 224){
      if (tid < 32) astf(P.Zb + p * 32 + tid, 0.f);          // clear Zb[p]
      DRAIN; __syncthreads();
      if (tid == 0) astw(P.arrY + bb * 4, tv);
    } else {
      if (tid == 0) astw(P.arrY + bb * 4, tv);
    }
    // ---- arrY wait (all 256 blocks) ----
    if (tid < 64){
      int spin = 0;
      for (;;){
        unsigned f0 = aldw(P.arrY + (tid      ) * 4);
        unsigned f1 = aldw(P.arrY + (tid +  64) * 4);
        unsigned f2 = aldw(P.arrY + (tid + 128) * 4);
        unsigned f3 = aldw(P.arrY + (tid + 192) * 4);
        if (__all((f0 >= tv) & (f1 >= tv) & (f2 >= tv) & (f3 >= tv))) break;
        if (++spin > SPINCAP) break;
        __builtin_amdgcn_s_sleep(1);
      }
    }
    __syncthreads();
    // ---- S34: scores + softmax + context partials (atomicAdd u[p], Zb[p]) ----
    {
      ull v = aldu((const ull*)(P.Xh1f + p * 16384 + b_att * 512) + tid);
      float f2[2]; __builtin_memcpy(f2, &v, 8);
      h1_s[tid * 2] = f2[0]; h1_s[tid * 2 + 1] = f2[1];
    }
    __syncthreads();
    {
      const int ti_l = tid >> 1, half = tid & 1;
      float s = 0.f;
      const unsigned swz = (unsigned)(ti_l & 7) << 4;
      for (int h8 = half * 256; h8 < half * 256 + 256; h8 += 8){
        unsigned byteoff = ((unsigned)(ti_l * 512 + h8) * 2u) ^ swz;
        s16x8 ev = *(const s16x8*)((const char*)enc_s + byteoff);
        #pragma unroll
        for (int e = 0; e < 8; ++e) s += b2f((unsigned short)ev[e]) * h1_s[h8 + e];
      }
      s += __shfl_xor(s, 1);
      if (half == 0) w_s[ti_l] = expf(s);       // no max-shift: |s| << 88
    }
    __syncthreads();
    {
      if (tid < 128){
        float z = w_s[tid];
        #pragma unroll
        for (int off = 1; off < 64; off <<= 1) z += __shfl_xor(z, off);
        if ((tid & 63) == 0) zred[tid >> 6] = z;
      }
      float a0 = 0.f, a1 = 0.f;
      const int hc = tid * 2;
      for (int ti = 0; ti < 128; ++ti){
        const float wvv = w_s[ti];
        unsigned byteoff = ((unsigned)(ti * 1024 + hc * 2)) ^ ((unsigned)(ti & 7) << 4);
        unsigned pk = *(const unsigned*)((const char*)enc_s + byteoff);
        a0 += wvv * b2f((unsigned short)(pk & 0xffffu));
        a1 += wvv * b2f((unsigned short)(pk >> 16));
      }
      unsafeAtomicAdd(P.u + p * 16384 + b_att * 512 + hc, a0);
      unsafeAtomicAdd(P.u + p * 16384 + b_att * 512 + hc + 1, a1);
      __syncthreads();
      if (tid == 0) unsafeAtomicAdd(P.Zb + p * 32 + b_att, zred[0] + zred[1]);
      DRAIN; __syncthreads();
      if (tid == 0) astw(P.marr + (b_att * 8 + tc) * 4, tv);
    }
  }
  // ---- tail: att_c(t=256), p=0 ----
  if (bb >= 128 && bb < 160){
    const int b = bb - 128;
    if (tid < 64){
      const unsigned want = (unsigned)T_;
      int spin = 0;
      for (;;){
        unsigned f = (tid < 8) ? aldw(P.marr + (b * 8 + tid) * 4) : want;
        if (__all(f >= want)) break;
        if (++spin > SPINCAP) break;
        __builtin_amdgcn_s_sleep(1);
      }
    }
    __syncthreads();
    const float rZ = 1.f / aldf(P.Zb + 0 * 32 + b);
    ull v = aldu((const ull*)(P.u + 0 * 16384 + b * 512) + tid);
    float f2[2]; __builtin_memcpy(f2, &v, 8);
    unsigned pk = (unsigned)f2b(f2[0] * rZ) | ((unsigned)f2b(f2[1] * rZ) << 16);
    *(unsigned*)(P.mlpin + ((size_t)256 * 32 + b) * 1024 + 512 + tid * 2) = pk;
  }
}

// ------------------------------------------------------------------
// B1: tanhv = tanh(mlpin @ W1^T + b1)   M=8224 N=512 K=1024, bf16 MFMA
__global__ __launch_bounds__(256) void kB1(Ptrs P){
  const int wid = blockIdx.x * 4 + (threadIdx.x >> 6);
  if (wid >= 129 * 8) return;
  const int mt = wid >> 3, nt = wid & 7;
  const int l = threadIdx.x & 63, lr = l & 15, lk = l >> 4;
  const int mr = mt * 64, nc = nt * 64;
  f32x4 acc[4][4] = {};
  for (int k0 = 0; k0 < 1024; k0 += 32){
    s16x8 af[4], bfm[4];
    #pragma unroll
    for (int f = 0; f < 4; ++f){
      int row = mr + f * 16 + lr; if (row > NROW_ - 1) row = NROW_ - 1;
      af[f] = *(const s16x8*)(P.mlpin + (size_t)row * 1024 + k0 + lk * 8);
      int col = nc + f * 16 + lr;
      bfm[f] = *(const s16x8*)(P.W1b + (size_t)col * 1024 + k0 + lk * 8);
    }
    #pragma unroll
    for (int fi = 0; fi < 4; ++fi)
      #pragma unroll
      for (int fj = 0; fj < 4; ++fj)
        acc[fi][fj] = __builtin_amdgcn_mfma_f32_16x16x32_bf16(af[fi], bfm[fj], acc[fi][fj], 0, 0, 0);
  }
  #pragma unroll
  for (int fi = 0; fi < 4; ++fi){
    #pragma unroll
    for (int jj = 0; jj < 4; ++jj){
      int m = mr + fi * 16 + lk * 4 + jj;
      if (m >= NROW_) continue;
      #pragma unroll
      for (int fj = 0; fj < 4; ++fj){
        int n = nc + fj * 16 + lr;
        P.tanhv[(size_t)m * 512 + n] = f2b(tanhf(acc[fi][fj][jj] + P.b1[n]));
      }
    }
  }
}

// B2: logits = tanhv @ W2^T + b2, fused exp-rowsum.  M=8224 N=10000 K=512
__global__ __launch_bounds__(256) void kB2(Ptrs P){
  const int wid = blockIdx.x * 4 + (threadIdx.x >> 6);
  if (wid >= 129 * 157) return;
  const int mt = wid / 157, nt = wid % 157;
  const int l = threadIdx.x & 63, lr = l & 15, lk = l >> 4;
  const int mr = mt * 64, nc = nt * 64;
  f32x4 acc[4][4] = {};
  for (int k0 = 0; k0 < 512; k0 += 32){
    s16x8 af[4], bfm[4];
    #pragma unroll
    for (int f = 0; f < 4; ++f){
      int row = mr + f * 16 + lr; if (row > NROW_ - 1) row = NROW_ - 1;
      af[f] = *(const s16x8*)(P.tanhv + (size_t)row * 512 + k0 + lk * 8);
      int col = nc + f * 16 + lr; if (col > V_ - 1) col = V_ - 1;
      bfm[f] = *(const s16x8*)(P.W2b + (size_t)col * 512 + k0 + lk * 8);
    }
    #pragma unroll
    for (int fi = 0; fi < 4; ++fi)
      #pragma unroll
      for (int fj = 0; fj < 4; ++fj)
        acc[fi][fj] = __builtin_amdgcn_mfma_f32_16x16x32_bf16(af[fi], bfm[fj], acc[fi][fj], 0, 0, 0);
  }
  #pragma unroll
  for (int fi = 0; fi < 4; ++fi){
    #pragma unroll
    for (int jj = 0; jj < 4; ++jj){
      const int m = mr + fi * 16 + lk * 4 + jj;
      float s = 0.f;
      #pragma unroll
      for (int fj = 0; fj < 4; ++fj){
        int n = nc + fj * 16 + lr;
        if (n < V_) s += expf(acc[fi][fj][jj] + P.b2[n]);
      }
      s += __shfl_xor(s, 1); s += __shfl_xor(s, 2);
      s += __shfl_xor(s, 4); s += __shfl_xor(s, 8);
      if (lr == 0 && m < NROW_) unsafeAtomicAdd(P.rowsum + m, s);
    }
  }
}

// label logit per row (one wave per row)
__global__ __launch_bounds__(256) void kL1(Ptrs P){
  const int wid = blockIdx.x * 4 + (threadIdx.x >> 6);
  if (wid >= NROW_) return;
  const int l = threadIdx.x & 63;
  const int t = wid >> 5, b = wid & 31;
  const int lab = (t < TO_) ? P.padded[b * TO_ + t] : 2;   // EOS=2
  float s = 0.f;
  s16x8 av = *(const s16x8*)(P.tanhv + (size_t)wid * 512 + l * 8);
  s16x8 wv = *(const s16x8*)(P.W2b + (size_t)lab * 512 + l * 8);
  #pragma unroll
  for (int e = 0; e < 8; ++e) s += b2f((unsigned short)av[e]) * b2f((unsigned short)wv[e]);
  #pragma unroll
  for (int off = 1; off < 64; off <<= 1) s += __shfl_xor(s, off);
  if (l == 0) P.lablog[wid] = s + P.b2[lab];
}

// final masked-NLL reduction
__global__ __launch_bounds__(512) void kL2(Ptrs P){
  __shared__ float ssum[8], scnt[8];
  const int tid = threadIdx.x;
  float sum = 0.f, cnt = 0.f;
  for (int rr = tid; rr < NROW_; rr += 512){
    int t = rr >> 5, b = rr & 31;
    int lab = (t < TO_) ? P.padded[b * TO_ + t] : 2;
    if (lab != 0){ sum += logf(P.rowsum[rr]) - P.lablog[rr]; cnt += 1.f; }
  }
  #pragma unroll
  for (int off = 1; off < 64; off <<= 1){ sum += __shfl_xor(sum, off); cnt += __shfl_xor(cnt, off); }
  if ((tid & 63) == 0){ ssum[tid >> 6] = sum; scnt[tid >> 6] = cnt; }
  __syncthreads();
  if (tid == 0){
    float S = 0.f, C = 0.f;
    for (int i = 0; i < 8; ++i){ S += ssum[i]; C += scnt[i]; }
    P.out[0] = S / fmaxf(C, 1.f);
  }
}

// ------------------------------------------------------------------
extern "C" void kernel_launch(void* const* d_in, const int* in_sizes, int n_in,
                              void* d_out, int out_size, void* d_ws, size_t ws_size,
                              hipStream_t stream){
  (void)in_sizes; (void)n_in; (void)out_size; (void)ws_size;
  Ptrs P;
  P.padded = (const int*)d_in[0];
  P.enc    = (const float*)d_in[1];
  P.emb    = (const float*)d_in[2];
  P.Wih0 = (const float*)d_in[3];  P.Whh0 = (const float*)d_in[4];
  P.bih0 = (const float*)d_in[5];  P.bhh0 = (const float*)d_in[6];
  P.Wih1 = (const float*)d_in[7];  P.Whh1 = (const float*)d_in[8];
  P.bih1 = (const float*)d_in[9];  P.bhh1 = (const float*)d_in[10];
  P.W1 = (const float*)d_in[11];   P.b1 = (const float*)d_in[12];
  P.W2 = (const float*)d_in[13];   P.b2 = (const float*)d_in[14];
  P.out = (float*)d_out;

  char* w = (char*)d_ws;
  size_t off = 0;
  auto take = [&](size_t bytes) -> void* {
    void* ptr = (void*)(w + off);
    off += (bytes + 255) & ~(size_t)255;
    return ptr;
  };
  P.mlpin  = (unsigned short*)take((size_t)T_ * B_ * 1024 * 2);   // 16.84 MB
  P.embt   = (unsigned short*)take((size_t)T_ * B_ * 512 * 2);    // 8.42 MB
  P.tanhv  = P.embt;                                              // overlay (post-kA)
  P.W0c    = (unsigned short*)take((size_t)2048 * 1536 * 2);      // 6.29 MB
  P.W1c    = (unsigned short*)take((size_t)2048 * 1024 * 2);      // 4.19 MB
  P.W2b    = P.W0c;                                               // overlay (post-kA)
  P.W1b    = (unsigned short*)take((size_t)512 * 1024 * 2);       // 1.05 MB
  P.bias0c = (float*)take(2048 * 4);
  P.bias1c = (float*)take(2048 * 4);
  P.u      = (float*)take(2 * 32 * 512 * 4);
  P.Zb     = (float*)take(2 * 32 * 4);
  P.Xh0    = (unsigned short*)take(2 * 32 * 512 * 2);
  P.Xh1    = (unsigned short*)take(2 * 32 * 512 * 2);
  P.Xh1f   = (float*)take(2 * 32 * 512 * 4);
  P.arrX   = (unsigned*)take(128 * 4 * 4);
  P.arrY   = (unsigned*)take(256 * 4 * 4);
  P.marr   = (unsigned*)take(256 * 4 * 4);
  P.ibar   = (unsigned*)take(256 * 4 * 4);
  P.rowsum = (float*)take(NROW_ * 4);
  P.lablog = (float*)take(NROW_ * 4);

  kprep<<<dim3(2048), dim3(256), 0, stream>>>(P);
  void* args[] = { (void*)&P };
  hipLaunchCooperativeKernel(kA, dim3(NB_), dim3(256), args, 0, stream);
  kprep2<<<dim3(1024), dim3(256), 0, stream>>>(P);
  kB1<<<dim3(258),  dim3(256), 0, stream>>>(P);
  kB2<<<dim3(5064), dim3(256), 0, stream>>>(P);
  kL1<<<dim3(2056), dim3(256), 0, stream>>>(P);
  kL2<<<dim3(1),    dim3(512), 0, stream>>>(P);
}